// Round 7
// baseline (329.825 us; speedup 1.0000x reference)
//
#include <hip/hip_runtime.h>
#include <hip/hip_bf16.h>
#include <math.h>

#define KBINS 5
#define NF 4
#define BV 3.0f

typedef float f32x4 __attribute__((ext_vector_type(4)));

// LDS tbl layout (floats):
//   [0,160):   f*40 + k*8 + {cw, iw, ch, h, dl, dr, d, s2}
//   [160,176): interior boundaries: f*4 + j = cumw[j+1], j=0..3
//   [176,179): mu, c0, ivar
#define BND_OFF 160
// one pair-factor scaled by 2^32; ld correction = -64*ln2
#define SCALE32 4294967296.0f
#define LDCORR 44.3614195558364998f

__global__ __launch_bounds__(256, 6) void nsf_all(
    const float* __restrict__ xin,
    const float* __restrict__ layers,
    const float* __restrict__ ip,
    float* __restrict__ out,
    long n) {
    __shared__ __align__(16) float tbl[184];
    const int t = threadIdx.x;
    // ---- prep phase 1: 13 writer threads, disjoint slots ----
    if (t < 12) {
        const int f = t & 3;
        const int role = t >> 2;
        const float* p = layers + f * (3 * KBINS - 1);
        if (role == 0) {
            float e[KBINS];
            float m = p[0];
            for (int i = 1; i < KBINS; ++i) m = fmaxf(m, p[i]);
            float s = 0.f;
            for (int i = 0; i < KBINS; ++i) { e[i] = expf(p[i] - m); s += e[i]; }
            float cs = 0.f;
            for (int k = 0; k < KBINS; ++k) {
                float Wk = (e[k] / s) * (2.f * BV);
                tbl[f * 40 + k * 8 + 0] = cs - BV;
                tbl[f * 40 + k * 8 + 1] = 1.f / Wk;
                cs += Wk;
                if (k < KBINS - 1) tbl[BND_OFF + f * 4 + k] = cs - BV;
            }
        } else if (role == 1) {
            float e[KBINS];
            float m = p[KBINS];
            for (int i = 1; i < KBINS; ++i) m = fmaxf(m, p[KBINS + i]);
            float s = 0.f;
            for (int i = 0; i < KBINS; ++i) { e[i] = expf(p[KBINS + i] - m); s += e[i]; }
            float cs = 0.f;
            for (int k = 0; k < KBINS; ++k) {
                float Hk = (e[k] / s) * (2.f * BV);
                tbl[f * 40 + k * 8 + 2] = cs - BV;
                tbl[f * 40 + k * 8 + 3] = Hk;
                cs += Hk;
            }
        } else {
            float dv[KBINS + 1];
            dv[0] = 1.f;
            dv[KBINS] = 1.f;
            for (int i = 0; i < KBINS - 1; ++i)
                dv[i + 1] = 2.f / (1.f + expf(-p[2 * KBINS + i]));
            for (int k = 0; k < KBINS; ++k) {
                tbl[f * 40 + k * 8 + 4] = dv[k];
                tbl[f * 40 + k * 8 + 5] = dv[k + 1];
            }
        }
    }
    if (t == 12) {
        tbl[176] = ip[0];
        tbl[177] = -0.5f * logf(2.f * (float)M_PI) - 0.5f * ip[1];
        tbl[178] = expf(-ip[1]);
    }
    __syncthreads();
    // ---- prep phase 2: derived per-bin d, s2 ----
    if (t < 32) {
        const int f = t >> 3, k = t & 7;
        if (k < KBINS) {
            float* b = &tbl[f * 40 + k * 8];
            float d = b[3] * b[1];               // h * iw
            b[6] = d;
            b[7] = fmaf(-2.f, d, b[4] + b[5]);   // dl+dr-2d
        }
    }
    __syncthreads();

    const float mu = tbl[176];
    const float c0 = tbl[177];
    const float ivar = tbl[178];

    const long n4 = n >> 2;
    const long tid = (long)blockIdx.x * blockDim.x + threadIdx.x;
    const long stride = (long)gridDim.x * blockDim.x;

    f32x4 cur;
    if (tid < n4) cur = reinterpret_cast<const f32x4*>(xin)[tid];

#pragma unroll 1
    for (long idx = tid; idx < n4; idx += stride) {
        const long nidx = idx + stride;
        f32x4 nxt = cur;
        if (nidx < n4) nxt = reinterpret_cast<const f32x4*>(xin)[nidx];

        float xo_[4] = {cur.x, cur.y, cur.z, cur.w};
        float xc[4];
        float pa[4], pb[4];
#pragma unroll
        for (int e = 0; e < 4; ++e) {
            xc[e] = fminf(fmaxf(xo_[e], -BV), BV);
            pa[e] = 1.f;
            pb[e] = 1.f;
        }

#pragma unroll
        for (int f = 0; f < NF; ++f) {
            const f32x4 bb = *reinterpret_cast<const f32x4*>(&tbl[BND_OFF + f * 4]);
            f32x4 lo[4], hi[4];
#pragma unroll
            for (int e = 0; e < 4; ++e) {
                int k = (xc[e] >= bb.x) + (xc[e] >= bb.y) + (xc[e] >= bb.z) + (xc[e] >= bb.w);
                const float* tt = &tbl[f * 40 + k * 8];
                lo[e] = *reinterpret_cast<const f32x4*>(tt);
                hi[e] = *reinterpret_cast<const f32x4*>(tt + 4);
            }
#pragma unroll
            for (int e = 0; e < 4; ++e) {
                float cw = lo[e].x, iw = lo[e].y, ch = lo[e].z, h = lo[e].w;
                float dl = hi[e].x, dr = hi[e].y, d = hi[e].z, s2 = hi[e].w;
                float th = (xc[e] - cw) * iw;
                float omt = 1.f - th;
                float tomt = th * omt;
                float th2 = th * th;
                float den = fmaf(s2, tomt, d);
                float rden = __builtin_amdgcn_rcpf(den);
                xc[e] = fmaf(h * fmaf(d, th2, dl * tomt), rden, ch);
                float Nn = fmaf(dr, th2, fmaf(d + d, tomt, dl * (omt * omt)));
                float g = d * rden;
                float r = (g * g) * Nn;
                // pair products; odd flows carry 2^32 scale (underflow insurance)
                if (f == 0) pa[e] *= r;
                else if (f == 1) pa[e] *= r * SCALE32;
                else if (f == 2) pb[e] *= r;
                else pb[e] *= r * SCALE32;
            }
        }

        f32x4 v0, v1, v2;
#pragma unroll
        for (int e = 0; e < 4; ++e) {
            const bool ins = (xo_[e] >= -BV) && (xo_[e] <= BV);
            float xf = ins ? xc[e] : xo_[e];
            float ld = ins ? (__logf(pa[e]) + __logf(pb[e]) - LDCORR) : 0.f;
            float xm = xf - mu;
            v0[e] = fmaf(-0.5f * ivar, xm * xm, c0);
            v1[e] = ld;
            v2[e] = xf;
        }
        __builtin_nontemporal_store(v0, reinterpret_cast<f32x4*>(out) + idx);
        __builtin_nontemporal_store(v1, reinterpret_cast<f32x4*>(out + n) + idx);
        __builtin_nontemporal_store(v2, reinterpret_cast<f32x4*>(out + 2 * n) + idx);
        cur = nxt;
    }

    // tail (n not divisible by 4)
    const long rem = n & 3;
    if (rem && tid < rem) {
        long i = n4 * 4 + tid;
        float x0 = xin[i];
        float xc = fminf(fmaxf(x0, -BV), BV);
        float pa = 1.f, pb = 1.f;
#pragma unroll
        for (int f = 0; f < NF; ++f) {
            const float* bbp = &tbl[BND_OFF + f * 4];
            int k = (xc >= bbp[0]) + (xc >= bbp[1]) + (xc >= bbp[2]) + (xc >= bbp[3]);
            const float* tt = &tbl[f * 40 + k * 8];
            float cw = tt[0], iw = tt[1], ch = tt[2], h = tt[3];
            float dl = tt[4], dr = tt[5], d = tt[6], s2 = tt[7];
            float th = (xc - cw) * iw;
            float omt = 1.f - th, tomt = th * omt, th2 = th * th;
            float den = fmaf(s2, tomt, d);
            float rden = __builtin_amdgcn_rcpf(den);
            xc = fmaf(h * fmaf(d, th2, dl * tomt), rden, ch);
            float Nn = fmaf(dr, th2, fmaf(d + d, tomt, dl * (omt * omt)));
            float g = d * rden;
            float r = (g * g) * Nn;
            if (f == 0) pa *= r;
            else if (f == 1) pa *= r * SCALE32;
            else if (f == 2) pb *= r;
            else pb *= r * SCALE32;
        }
        const bool ins = (x0 >= -BV) && (x0 <= BV);
        float xf = ins ? xc : x0;
        float ld = ins ? (__logf(pa) + __logf(pb) - LDCORR) : 0.f;
        float xm = xf - mu;
        out[i] = fmaf(-0.5f * ivar, xm * xm, c0);
        out[n + i] = ld;
        out[2 * n + i] = xf;
    }
}

extern "C" void kernel_launch(void* const* d_in, const int* in_sizes, int n_in,
                              void* d_out, int out_size, void* d_ws, size_t ws_size,
                              hipStream_t stream) {
    const float* x = (const float*)d_in[0];
    const float* layers = (const float*)d_in[1];
    const float* ip = (const float*)d_in[2];
    float* out = (float*)d_out;
    const long n = (long)in_sizes[0];

    const long n4 = (n + 3) >> 2;
    long blocks = (n4 + 255) / 256;
    if (blocks > 1536) blocks = 1536;
    if (blocks < 1) blocks = 1;
    hipLaunchKernelGGL(nsf_all, dim3((int)blocks), dim3(256), 0, stream, x, layers, ip, out, n);
}

// Round 8
// 168.616 us; speedup vs baseline: 1.9561x; 1.9561x over previous
//
#include <hip/hip_runtime.h>
#include <hip/hip_bf16.h>
#include <math.h>

#define KBINS 5
#define NF 4
#define BV 3.0f

typedef float f32x4 __attribute__((ext_vector_type(4)));

// LDS tbl layout (floats):
//   [0,160):   f*40 + k*8 + {cw, iw, ch, h, dl, dr, d, s2}
//   [160,176): interior boundaries: f*4 + j = cumw[j+1], j=0..3
//   [176,179): mu, c0, ivar
#define BND_OFF 160
// one pair-factor scaled by 2^32; ld correction = -64*ln2
#define SCALE32 4294967296.0f
#define LDCORR 44.3614195558364998f

__global__ __launch_bounds__(256, 4) void nsf_all(
    const float* __restrict__ xin,
    const float* __restrict__ layers,
    const float* __restrict__ ip,
    float* __restrict__ out,
    long n) {
    __shared__ __align__(16) float tbl[184];
    const int t = threadIdx.x;
    // ---- prep phase 1: 13 writer threads, disjoint slots ----
    if (t < 12) {
        const int f = t & 3;
        const int role = t >> 2;
        const float* p = layers + f * (3 * KBINS - 1);
        if (role == 0) {
            float e[KBINS];
            float m = p[0];
            for (int i = 1; i < KBINS; ++i) m = fmaxf(m, p[i]);
            float s = 0.f;
            for (int i = 0; i < KBINS; ++i) { e[i] = expf(p[i] - m); s += e[i]; }
            float cs = 0.f;
            for (int k = 0; k < KBINS; ++k) {
                float Wk = (e[k] / s) * (2.f * BV);
                tbl[f * 40 + k * 8 + 0] = cs - BV;
                tbl[f * 40 + k * 8 + 1] = 1.f / Wk;
                cs += Wk;
                if (k < KBINS - 1) tbl[BND_OFF + f * 4 + k] = cs - BV;
            }
        } else if (role == 1) {
            float e[KBINS];
            float m = p[KBINS];
            for (int i = 1; i < KBINS; ++i) m = fmaxf(m, p[KBINS + i]);
            float s = 0.f;
            for (int i = 0; i < KBINS; ++i) { e[i] = expf(p[KBINS + i] - m); s += e[i]; }
            float cs = 0.f;
            for (int k = 0; k < KBINS; ++k) {
                float Hk = (e[k] / s) * (2.f * BV);
                tbl[f * 40 + k * 8 + 2] = cs - BV;
                tbl[f * 40 + k * 8 + 3] = Hk;
                cs += Hk;
            }
        } else {
            float dv[KBINS + 1];
            dv[0] = 1.f;
            dv[KBINS] = 1.f;
            for (int i = 0; i < KBINS - 1; ++i)
                dv[i + 1] = 2.f / (1.f + expf(-p[2 * KBINS + i]));
            for (int k = 0; k < KBINS; ++k) {
                tbl[f * 40 + k * 8 + 4] = dv[k];
                tbl[f * 40 + k * 8 + 5] = dv[k + 1];
            }
        }
    }
    if (t == 12) {
        tbl[176] = ip[0];
        tbl[177] = -0.5f * logf(2.f * (float)M_PI) - 0.5f * ip[1];
        tbl[178] = expf(-ip[1]);
    }
    __syncthreads();
    // ---- prep phase 2: derived per-bin d, s2 ----
    if (t < 32) {
        const int f = t >> 3, k = t & 7;
        if (k < KBINS) {
            float* b = &tbl[f * 40 + k * 8];
            float d = b[3] * b[1];               // h * iw
            b[6] = d;
            b[7] = fmaf(-2.f, d, b[4] + b[5]);   // dl+dr-2d
        }
    }
    __syncthreads();

    const float mu = tbl[176];
    const float c0 = tbl[177];
    const float ivar = tbl[178];

    const long n4 = n >> 2;
    const long tid = (long)blockIdx.x * blockDim.x + threadIdx.x;
    const long stride = (long)gridDim.x * blockDim.x;

    f32x4 cur;
    if (tid < n4) cur = reinterpret_cast<const f32x4*>(xin)[tid];

#pragma unroll 1
    for (long idx = tid; idx < n4; idx += stride) {
        const long nidx = idx + stride;
        f32x4 nxt = cur;
        if (nidx < n4) nxt = reinterpret_cast<const f32x4*>(xin)[nidx];

        float xo_[4] = {cur.x, cur.y, cur.z, cur.w};
        float xc[4];
        bool ins[4];
        float pa[4], pb[4];
#pragma unroll
        for (int e = 0; e < 4; ++e) {
            xc[e] = fminf(fmaxf(xo_[e], -BV), BV);
            ins[e] = (xo_[e] == xc[e]);
            pa[e] = 1.f;
            pb[e] = 1.f;
        }

#pragma unroll
        for (int f = 0; f < NF; ++f) {
            const f32x4 bb = *reinterpret_cast<const f32x4*>(&tbl[BND_OFF + f * 4]);
            f32x4 lo[4], hi[4];
#pragma unroll
            for (int e = 0; e < 4; ++e) {
                int k = (xc[e] >= bb.x) + (xc[e] >= bb.y) + (xc[e] >= bb.z) + (xc[e] >= bb.w);
                const float* tt = &tbl[f * 40 + k * 8];
                lo[e] = *reinterpret_cast<const f32x4*>(tt);
                hi[e] = *reinterpret_cast<const f32x4*>(tt + 4);
            }
#pragma unroll
            for (int e = 0; e < 4; ++e) {
                float cw = lo[e].x, iw = lo[e].y, ch = lo[e].z, h = lo[e].w;
                float dl = hi[e].x, dr = hi[e].y, d = hi[e].z, s2 = hi[e].w;
                float th = (xc[e] - cw) * iw;
                float omt = 1.f - th;
                float tomt = th * omt;
                float th2 = th * th;
                float den = fmaf(s2, tomt, d);
                float rden = __builtin_amdgcn_rcpf(den);
                xc[e] = fmaf(h * fmaf(d, th2, dl * tomt), rden, ch);
                float Nn = fmaf(dr, th2, fmaf(d + d, tomt, dl * (omt * omt)));
                float g = d * rden;
                float r = (g * g) * Nn;
                // pair products; odd flows carry 2^32 scale (underflow insurance)
                if (f == 0) pa[e] *= r;
                else if (f == 1) pa[e] *= r * SCALE32;
                else if (f == 2) pb[e] *= r;
                else pb[e] *= r * SCALE32;
            }
        }

        f32x4 v0, v1, v2;
#pragma unroll
        for (int e = 0; e < 4; ++e) {
            float xf = ins[e] ? xc[e] : xo_[e];
            float ld = ins[e] ? (__logf(pa[e]) + __logf(pb[e]) - LDCORR) : 0.f;
            float xm = xf - mu;
            v0[e] = fmaf(-0.5f * ivar, xm * xm, c0);
            v1[e] = ld;
            v2[e] = xf;
        }
        __builtin_nontemporal_store(v0, reinterpret_cast<f32x4*>(out) + idx);
        __builtin_nontemporal_store(v1, reinterpret_cast<f32x4*>(out + n) + idx);
        __builtin_nontemporal_store(v2, reinterpret_cast<f32x4*>(out + 2 * n) + idx);
        cur = nxt;
    }

    // tail (n not divisible by 4)
    const long rem = n & 3;
    if (rem && tid < rem) {
        long i = n4 * 4 + tid;
        float x0 = xin[i];
        float xc = fminf(fmaxf(x0, -BV), BV);
        const bool ins = (x0 == xc);
        float pa = 1.f, pb = 1.f;
#pragma unroll
        for (int f = 0; f < NF; ++f) {
            const float* bbp = &tbl[BND_OFF + f * 4];
            int k = (xc >= bbp[0]) + (xc >= bbp[1]) + (xc >= bbp[2]) + (xc >= bbp[3]);
            const float* tt = &tbl[f * 40 + k * 8];
            float cw = tt[0], iw = tt[1], ch = tt[2], h = tt[3];
            float dl = tt[4], dr = tt[5], d = tt[6], s2 = tt[7];
            float th = (xc - cw) * iw;
            float omt = 1.f - th, tomt = th * omt, th2 = th * th;
            float den = fmaf(s2, tomt, d);
            float rden = __builtin_amdgcn_rcpf(den);
            xc = fmaf(h * fmaf(d, th2, dl * tomt), rden, ch);
            float Nn = fmaf(dr, th2, fmaf(d + d, tomt, dl * (omt * omt)));
            float g = d * rden;
            float r = (g * g) * Nn;
            if (f == 0) pa *= r;
            else if (f == 1) pa *= r * SCALE32;
            else if (f == 2) pb *= r;
            else pb *= r * SCALE32;
        }
        float xf = ins ? xc : x0;
        float ld = ins ? (__logf(pa) + __logf(pb) - LDCORR) : 0.f;
        float xm = xf - mu;
        out[i] = fmaf(-0.5f * ivar, xm * xm, c0);
        out[n + i] = ld;
        out[2 * n + i] = xf;
    }
}

extern "C" void kernel_launch(void* const* d_in, const int* in_sizes, int n_in,
                              void* d_out, int out_size, void* d_ws, size_t ws_size,
                              hipStream_t stream) {
    const float* x = (const float*)d_in[0];
    const float* layers = (const float*)d_in[1];
    const float* ip = (const float*)d_in[2];
    float* out = (float*)d_out;
    const long n = (long)in_sizes[0];

    const long n4 = (n + 3) >> 2;
    long blocks = (n4 + 255) / 256;
    if (blocks > 2048) blocks = 2048;
    if (blocks < 1) blocks = 1;
    hipLaunchKernelGGL(nsf_all, dim3((int)blocks), dim3(256), 0, stream, x, layers, ip, out, n);
}

// Round 9
// 52.085 us; speedup vs baseline: 6.3324x; 3.2373x over previous
//
#include <hip/hip_runtime.h>
#include <hip/hip_bf16.h>
#include <math.h>

#define KBINS 5
#define NF 4
#define BV 3.0f

typedef float f32x4 __attribute__((ext_vector_type(4)));
typedef float f32x2 __attribute__((ext_vector_type(2)));

// LDS tbl layout (floats):
//   [0,160):   f*40 + k*8 + {cw, iw, ch, h, dl, dr, -, -}   (stride 8 for b128 align)
//   [160,176): interior boundaries: f*4 + j = cumw[j+1], j=0..3
//   [176,179): mu, c0, ivar
#define BND_OFF 160

__global__ __launch_bounds__(256, 4) void nsf_all(
    const float* __restrict__ xin,
    const float* __restrict__ layers,
    const float* __restrict__ ip,
    float* __restrict__ out,
    long n) {
    __shared__ __align__(16) float tbl[184];
    const int t = threadIdx.x;
    // ---- in-block prep: 13 writer threads, disjoint slots (proven r5 shape) ----
    if (t < 12) {
        const int f = t & 3;
        const int role = t >> 2;
        const float* p = layers + f * (3 * KBINS - 1);
        if (role == 0) {
            float e[KBINS];
            float m = p[0];
            for (int i = 1; i < KBINS; ++i) m = fmaxf(m, p[i]);
            float s = 0.f;
            for (int i = 0; i < KBINS; ++i) { e[i] = expf(p[i] - m); s += e[i]; }
            float cs = 0.f;
            for (int k = 0; k < KBINS; ++k) {
                float Wk = (e[k] / s) * (2.f * BV);
                tbl[f * 40 + k * 8 + 0] = cs - BV;
                tbl[f * 40 + k * 8 + 1] = 1.f / Wk;
                cs += Wk;
                if (k < KBINS - 1) tbl[BND_OFF + f * 4 + k] = cs - BV;
            }
        } else if (role == 1) {
            float e[KBINS];
            float m = p[KBINS];
            for (int i = 1; i < KBINS; ++i) m = fmaxf(m, p[KBINS + i]);
            float s = 0.f;
            for (int i = 0; i < KBINS; ++i) { e[i] = expf(p[KBINS + i] - m); s += e[i]; }
            float cs = 0.f;
            for (int k = 0; k < KBINS; ++k) {
                float Hk = (e[k] / s) * (2.f * BV);
                tbl[f * 40 + k * 8 + 2] = cs - BV;
                tbl[f * 40 + k * 8 + 3] = Hk;
                cs += Hk;
            }
        } else {
            float dv[KBINS + 1];
            dv[0] = 1.f;
            dv[KBINS] = 1.f;
            for (int i = 0; i < KBINS - 1; ++i)
                dv[i + 1] = 2.f / (1.f + expf(-p[2 * KBINS + i]));
            for (int k = 0; k < KBINS; ++k) {
                tbl[f * 40 + k * 8 + 4] = dv[k];
                tbl[f * 40 + k * 8 + 5] = dv[k + 1];
            }
        }
    }
    if (t == 12) {
        tbl[176] = ip[0];
        tbl[177] = -0.5f * logf(2.f * (float)M_PI) - 0.5f * ip[1];
        tbl[178] = expf(-ip[1]);
    }
    __syncthreads();

    const float mu = tbl[176];
    const float c0 = tbl[177];
    const float ivar = tbl[178];

    const long n4 = n >> 2;
    const long q = (long)blockIdx.x * blockDim.x + threadIdx.x;

    if (q < n4) {
        const f32x4 xv = reinterpret_cast<const f32x4*>(xin)[q];
        float xc[4];
        float lda[4];
#pragma unroll
        for (int e = 0; e < 4; ++e) {
            xc[e] = fminf(fmaxf(xv[e], -BV), BV);
            lda[e] = 0.f;
        }

#pragma unroll
        for (int f = 0; f < NF; ++f) {
            const f32x4 bb = *reinterpret_cast<const f32x4*>(&tbl[BND_OFF + f * 4]);
            f32x4 lo[4];
            f32x2 dd[4];
#pragma unroll
            for (int e = 0; e < 4; ++e) {
                int k = (xc[e] >= bb.x) + (xc[e] >= bb.y) + (xc[e] >= bb.z) + (xc[e] >= bb.w);
                const float* tt = &tbl[f * 40 + k * 8];
                lo[e] = *reinterpret_cast<const f32x4*>(tt);
                dd[e] = *reinterpret_cast<const f32x2*>(tt + 4);
            }
#pragma unroll
            for (int e = 0; e < 4; ++e) {
                float cw = lo[e].x, iw = lo[e].y, ch = lo[e].z, h = lo[e].w;
                float dl = dd[e].x, dr = dd[e].y;
                float d = h * iw;
                float s2 = fmaf(-2.f, d, dl + dr);
                float th = (xc[e] - cw) * iw;
                float omt = 1.f - th;
                float tomt = th * omt;
                float th2 = th * th;
                float den = fmaf(s2, tomt, d);
                float rden = __builtin_amdgcn_rcpf(den);
                xc[e] = fmaf(h * fmaf(d, th2, dl * tomt), rden, ch);
                float Nn = fmaf(dr, th2, fmaf(d + d, tomt, dl * (omt * omt)));
                float g = d * rden;
                lda[e] += __logf((g * g) * Nn);
            }
        }

        f32x4 v0, v1, v2;
#pragma unroll
        for (int e = 0; e < 4; ++e) {
            const bool ins = (xv[e] >= -BV) && (xv[e] <= BV);
            float xf = ins ? xc[e] : xv[e];
            float ld = ins ? lda[e] : 0.f;
            float xm = xf - mu;
            v0[e] = fmaf(-0.5f * ivar, xm * xm, c0);
            v1[e] = ld;
            v2[e] = xf;
        }
        __builtin_nontemporal_store(v0, reinterpret_cast<f32x4*>(out) + q);
        __builtin_nontemporal_store(v1, reinterpret_cast<f32x4*>(out + n) + q);
        __builtin_nontemporal_store(v2, reinterpret_cast<f32x4*>(out + 2 * n) + q);
    }

    // tail (n not divisible by 4; n = 2^23 here so normally empty)
    const long rem = n & 3;
    if (rem && q < rem) {
        long i = n4 * 4 + q;
        float x0 = xin[i];
        float xc = fminf(fmaxf(x0, -BV), BV);
        float lda = 0.f;
#pragma unroll
        for (int f = 0; f < NF; ++f) {
            const float* bbp = &tbl[BND_OFF + f * 4];
            int k = (xc >= bbp[0]) + (xc >= bbp[1]) + (xc >= bbp[2]) + (xc >= bbp[3]);
            const float* tt = &tbl[f * 40 + k * 8];
            float cw = tt[0], iw = tt[1], ch = tt[2], h = tt[3];
            float dl = tt[4], dr = tt[5];
            float d = h * iw;
            float s2 = fmaf(-2.f, d, dl + dr);
            float th = (xc - cw) * iw;
            float omt = 1.f - th, tomt = th * omt, th2 = th * th;
            float den = fmaf(s2, tomt, d);
            float rden = __builtin_amdgcn_rcpf(den);
            xc = fmaf(h * fmaf(d, th2, dl * tomt), rden, ch);
            float Nn = fmaf(dr, th2, fmaf(d + d, tomt, dl * (omt * omt)));
            float g = d * rden;
            lda += __logf((g * g) * Nn);
        }
        const bool ins = (x0 >= -BV) && (x0 <= BV);
        float xf = ins ? xc : x0;
        float ld = ins ? lda : 0.f;
        float xm = xf - mu;
        out[i] = fmaf(-0.5f * ivar, xm * xm, c0);
        out[n + i] = ld;
        out[2 * n + i] = xf;
    }
}

extern "C" void kernel_launch(void* const* d_in, const int* in_sizes, int n_in,
                              void* d_out, int out_size, void* d_ws, size_t ws_size,
                              hipStream_t stream) {
    const float* x = (const float*)d_in[0];
    const float* layers = (const float*)d_in[1];
    const float* ip = (const float*)d_in[2];
    float* out = (float*)d_out;
    const long n = (long)in_sizes[0];

    const long n4 = (n + 3) >> 2;
    long blocks = (n4 + 255) / 256;
    if (blocks < 1) blocks = 1;
    hipLaunchKernelGGL(nsf_all, dim3((int)blocks), dim3(256), 0, stream, x, layers, ip, out, n);
}